// Round 1
// baseline (122.144 us; speedup 1.0000x reference)
//
#include <hip/hip_runtime.h>
#include <hip/hip_bf16.h>

#define N_ 8192
#define D_ 256
#define BM 128
#define BK 32
#define NB (N_ / BM)  // 64

typedef __bf16 bf16x8 __attribute__((ext_vector_type(8)));
typedef float f32x4 __attribute__((ext_vector_type(4)));

// ---------------- fp32 -> bf16 convert ----------------
__global__ void cvt_kernel(const float4* __restrict__ in, ushort4* __restrict__ out, int n4) {
  int i = blockIdx.x * blockDim.x + threadIdx.x;
  if (i >= n4) return;
  float4 v = in[i];
  union { __hip_bfloat16 h[4]; ushort4 u; } t;
  t.h[0] = __float2bfloat16(v.x);
  t.h[1] = __float2bfloat16(v.y);
  t.h[2] = __float2bfloat16(v.z);
  t.h[3] = __float2bfloat16(v.w);
  out[i] = t.u;
}

// ---------------- main fused GEMM + masked reduction ----------------
// acc layout in ws (doubles): [0]=pos_cnt [1]=pos_sim_sum [2]=neg_sim_sum
//                             [3]=lp_sum  [4]=lp_cnt [5]=ln_sum [6]=ln_cnt
__global__ __launch_bounds__(256, 2) void simloss_kernel(
    const __hip_bfloat16* __restrict__ Xb, const int* __restrict__ tg,
    double* __restrict__ accd) {
  const int bi = blockIdx.y, bj = blockIdx.x;
  if (bi > bj) return;  // symmetric: only upper triangle of block-tiles
  __shared__ __hip_bfloat16 Asm[BM][BK];  // 8 KB
  __shared__ __hip_bfloat16 Bsm[BM][BK];  // 8 KB
  const int tid = threadIdx.x;
  const int lane = tid & 63, wv = tid >> 6;
  const int wr = wv >> 1, wc = wv & 1;  // wave -> 64x64 sub-tile
  const int rowA0 = bi * BM, rowB0 = bj * BM;

  f32x4 acc[4][4] = {};

  const __bf16* As = (const __bf16*)&Asm[0][0];
  const __bf16* Bs = (const __bf16*)&Bsm[0][0];
  const int fr = lane & 15;        // fragment row (A) / col (B)
  const int ko = (lane >> 4) * 8;  // k offset within 32

  for (int kt = 0; kt < D_ / BK; ++kt) {
    __syncthreads();  // previous tile's reads done before overwrite
    // stage A,B tiles: 512 chunks of 16B each; chunk c -> row c>>2, kblk c&3
#pragma unroll
    for (int q = 0; q < 2; ++q) {
      int c = q * 256 + wv * 64 + lane;
      int row = c >> 2, kb = c & 3;
      const __hip_bfloat16* gA = Xb + (size_t)(rowA0 + row) * D_ + kt * BK + kb * 8;
      const __hip_bfloat16* gB = Xb + (size_t)(rowB0 + row) * D_ + kt * BK + kb * 8;
      char* lA = (char*)&Asm[0][0] + (q * 256 + wv * 64) * 16;  // wave-uniform base
      char* lB = (char*)&Bsm[0][0] + (q * 256 + wv * 64) * 16;
      __builtin_amdgcn_global_load_lds((__attribute__((address_space(1))) void*)gA,
                                       (__attribute__((address_space(3))) void*)lA, 16, 0, 0);
      __builtin_amdgcn_global_load_lds((__attribute__((address_space(1))) void*)gB,
                                       (__attribute__((address_space(3))) void*)lB, 16, 0, 0);
    }
    __syncthreads();  // compiler drains vmcnt before barrier

    bf16x8 af[4], bfr[4];
#pragma unroll
    for (int m = 0; m < 4; ++m)
      af[m] = *(const bf16x8*)(As + (wr * 64 + m * 16 + fr) * BK + ko);
#pragma unroll
    for (int n = 0; n < 4; ++n)
      bfr[n] = *(const bf16x8*)(Bs + (wc * 64 + n * 16 + fr) * BK + ko);
#pragma unroll
    for (int m = 0; m < 4; ++m)
#pragma unroll
      for (int n = 0; n < 4; ++n)
        acc[m][n] = __builtin_amdgcn_mfma_f32_16x16x32_bf16(af[m], bfr[n], acc[m][n], 0, 0, 0);
  }

  // epilogue: C/D layout col=lane&15, row=(lane>>4)*4+reg  [guide §3, m89]
  const int cRow = (lane >> 4) * 4, cCol = lane & 15;
  int tj[4], ti[4][4];
#pragma unroll
  for (int n = 0; n < 4; ++n) tj[n] = tg[rowB0 + wc * 64 + n * 16 + cCol];
#pragma unroll
  for (int m = 0; m < 4; ++m)
#pragma unroll
    for (int r = 0; r < 4; ++r) ti[m][r] = tg[rowA0 + wr * 64 + m * 16 + cRow + r];

  float pc = 0.f, ps = 0.f, ns = 0.f;
#pragma unroll
  for (int m = 0; m < 4; ++m)
#pragma unroll
    for (int n = 0; n < 4; ++n)
#pragma unroll
      for (int r = 0; r < 4; ++r) {
        float s = acc[m][n][r];
        bool same = (ti[m][r] == tj[n]);
        if (same & (s < 0.9f)) { pc += 1.0f; ps += s; }
        if ((!same) & (s > 0.5f)) { ns += s; }
      }

  // wave reduce then cross-wave via LDS
#pragma unroll
  for (int off = 32; off > 0; off >>= 1) {
    pc += __shfl_down(pc, off);
    ps += __shfl_down(ps, off);
    ns += __shfl_down(ns, off);
  }
  __shared__ float red[3][4];
  if (lane == 0) { red[0][wv] = pc; red[1][wv] = ps; red[2][wv] = ns; }
  __syncthreads();
  if (tid == 0) {
    double w = (bi == bj) ? 1.0 : 2.0;  // off-diag block-tiles count twice
    atomicAdd(&accd[0], w * (double)(red[0][0] + red[0][1] + red[0][2] + red[0][3]));
    atomicAdd(&accd[1], w * (double)(red[1][0] + red[1][1] + red[1][2] + red[1][3]));
    atomicAdd(&accd[2], w * (double)(red[2][0] + red[2][1] + red[2][2] + red[2][3]));
  }
}

// ---------------- last-row stats in fp64 (sim<1.0 diagonal test!) ----------------
__global__ void lastrow_kernel(const float* __restrict__ X, const int* __restrict__ tg,
                               double* __restrict__ accd) {
  int j = blockIdx.x * blockDim.x + threadIdx.x;  // 8192 threads, one column each
  const float4* xr = (const float4*)(X + (size_t)(N_ - 1) * D_);
  const float4* yj = (const float4*)(X + (size_t)j * D_);
  double s = 0.0;
#pragma unroll 4
  for (int k = 0; k < D_ / 4; ++k) {
    float4 a = xr[k], b = yj[k];
    s += (double)a.x * b.x + (double)a.y * b.y + (double)a.z * b.z + (double)a.w * b.w;
  }
  float sf = (float)s;  // round to fp32, then apply fp32 comparisons like the reference
  bool same = (tg[j] == tg[N_ - 1]);
  float v[4] = {0.f, 0.f, 0.f, 0.f};
  if (same && sf < 1.0f) { v[0] = sf; v[1] = 1.f; }  // lp: same & sim<1.0
  if (!same) { v[2] = sf; v[3] = 1.f; }              // ln: all diff-class
#pragma unroll
  for (int off = 32; off > 0; off >>= 1)
#pragma unroll
    for (int q = 0; q < 4; ++q) v[q] += __shfl_down(v[q], off);
  if ((threadIdx.x & 63) == 0)
#pragma unroll
    for (int q = 0; q < 4; ++q) atomicAdd(&accd[3 + q], (double)v[q]);
}

// ---------------- finalize ----------------
__global__ void finalize_kernel(const double* __restrict__ accd, float* __restrict__ out) {
  double loss = (accd[0] - accd[1] + accd[2]) / (double)N_;
  out[0] = (float)loss;
  out[1] = 0.0f;  // prec: reference never increments c
  out[2] = (float)(accd[3] / fmax(accd[4], 1.0));
  out[3] = (float)(accd[5] / fmax(accd[6], 1.0));
}

extern "C" void kernel_launch(void* const* d_in, const int* in_sizes, int n_in,
                              void* d_out, int out_size, void* d_ws, size_t ws_size,
                              hipStream_t stream) {
  const float* X = (const float*)d_in[0];
  const int* tg = (const int*)d_in[1];
  float* out = (float*)d_out;
  double* accd = (double*)d_ws;
  __hip_bfloat16* Xb = (__hip_bfloat16*)((char*)d_ws + 64);

  hipMemsetAsync(d_ws, 0, 64, stream);  // zero the 8 accumulator doubles every call

  int n4 = N_ * D_ / 4;
  cvt_kernel<<<(n4 + 255) / 256, 256, 0, stream>>>((const float4*)X, (ushort4*)Xb, n4);

  dim3 grid(NB, NB);
  simloss_kernel<<<grid, 256, 0, stream>>>(Xb, tg, accd);

  lastrow_kernel<<<N_ / 256, 256, 0, stream>>>(X, tg, accd);
  finalize_kernel<<<1, 1, 0, stream>>>(accd, out);
}

// Round 2
// 73.637 us; speedup vs baseline: 1.6587x; 1.6587x over previous
//
#include <hip/hip_runtime.h>
#include <hip/hip_bf16.h>

#define N_ 8192
#define D_ 256
#define BM 128
#define BK 32
#define NB (N_ / BM)            // 64
#define NT (NB * (NB + 1) / 2)  // 2080 triangular tiles
#define KSTEPS (D_ / BK)        // 8

typedef __bf16 bf16x8 __attribute__((ext_vector_type(8)));
typedef float f32x4 __attribute__((ext_vector_type(4)));

// ---------------- fp32 -> bf16 convert ----------------
__global__ void cvt_kernel(const float4* __restrict__ in, ushort4* __restrict__ out, int n4) {
  int i = blockIdx.x * blockDim.x + threadIdx.x;
  if (i >= n4) return;
  float4 v = in[i];
  union { __hip_bfloat16 h[4]; ushort4 u; } t;
  t.h[0] = __float2bfloat16(v.x);
  t.h[1] = __float2bfloat16(v.y);
  t.h[2] = __float2bfloat16(v.z);
  t.h[3] = __float2bfloat16(v.w);
  out[i] = t.u;
}

// ws accumulator layout (doubles):
//  [32][3] per-slot {pos_cnt, pos_sim_sum, neg_sim_sum}  (slots 0..95)
//  [96..99] lastrow {lp_sum, lp_cnt, ln_sum, ln_cnt}
__global__ __launch_bounds__(256, 4) void simloss_kernel(
    const __hip_bfloat16* __restrict__ Xb, const int* __restrict__ tg,
    double* __restrict__ accd) {
  // ---- decode triangular tile index -> (bi, bj), bi <= bj ----
  const int t = blockIdx.x;
  int bi = (int)((2.0 * NB + 1.0 -
                  sqrt((2.0 * NB + 1.0) * (2.0 * NB + 1.0) - 8.0 * (double)t)) * 0.5);
  while ((bi + 1) * NB - ((bi + 1) * bi) / 2 <= t) ++bi;  // offset(bi+1) <= t
  while (bi * NB - (bi * (bi - 1)) / 2 > t) --bi;         // offset(bi) > t
  const int bj = bi + (t - (bi * NB - (bi * (bi - 1)) / 2));

  __shared__ __hip_bfloat16 Asm[2][BM * BK];  // 2 x 8 KB
  __shared__ __hip_bfloat16 Bsm[2][BM * BK];  // 2 x 8 KB   (32 KB total)

  const int tid = threadIdx.x;
  const int lane = tid & 63, wv = tid >> 6;
  const int wr = wv >> 1, wc = wv & 1;  // wave -> 64x64 sub-tile of 128x128
  const int rowA0 = bi * BM, rowB0 = bj * BM;

  f32x4 acc[4][4] = {};

  const int fr = lane & 15;              // fragment row within 16
  const int sl = lane >> 4;              // 16B slot 0..3 (pre-swizzle)
  const int swz = sl ^ (fr & 3);         // row&3 == fr&3 for all frag rows
  const int koff = swz * 8;              // bf16 element offset within row

  // stage one BK-tile (A+B) into buffer `buf`; LDS dest linear,
  // global source pre-swizzled (slot ^ (row&3)) so swizzled reads see the
  // right data (guide rule #21).
#define STAGE(buf, kt)                                                             \
  {                                                                                \
    _Pragma("unroll") for (int q = 0; q < 2; ++q) {                                \
      int c = (wv * 2 + q) * 64 + lane; /* chunk 0..511 */                         \
      int row = c >> 2, slot = c & 3;                                              \
      int sw = slot ^ (row & 3);                                                   \
      const __hip_bfloat16* gA = Xb + (size_t)(rowA0 + row) * D_ + (kt)*BK + sw * 8; \
      const __hip_bfloat16* gB = Xb + (size_t)(rowB0 + row) * D_ + (kt)*BK + sw * 8; \
      char* lA = (char*)&Asm[buf][0] + (wv * 2 + q) * 1024;                        \
      char* lB = (char*)&Bsm[buf][0] + (wv * 2 + q) * 1024;                        \
      __builtin_amdgcn_global_load_lds((__attribute__((address_space(1))) void*)gA, \
                                       (__attribute__((address_space(3))) void*)lA, \
                                       16, 0, 0);                                  \
      __builtin_amdgcn_global_load_lds((__attribute__((address_space(1))) void*)gB, \
                                       (__attribute__((address_space(3))) void*)lB, \
                                       16, 0, 0);                                  \
    }                                                                              \
  }

  STAGE(0, 0);
  __syncthreads();

  int cur = 0;
  for (int kt = 0; kt < KSTEPS; ++kt) {
    if (kt < KSTEPS - 1) STAGE(cur ^ 1, kt + 1);  // prefetch next tile
    const __bf16* As = (const __bf16*)&Asm[cur][0];
    const __bf16* Bs = (const __bf16*)&Bsm[cur][0];
    bf16x8 af[4], bfr[4];
#pragma unroll
    for (int m = 0; m < 4; ++m)
      af[m] = *(const bf16x8*)(As + (wr * 64 + m * 16 + fr) * BK + koff);
#pragma unroll
    for (int n = 0; n < 4; ++n)
      bfr[n] = *(const bf16x8*)(Bs + (wc * 64 + n * 16 + fr) * BK + koff);
#pragma unroll
    for (int m = 0; m < 4; ++m)
#pragma unroll
      for (int n = 0; n < 4; ++n)
        acc[m][n] = __builtin_amdgcn_mfma_f32_16x16x32_bf16(af[m], bfr[n], acc[m][n], 0, 0, 0);
    __syncthreads();  // stage of next buf complete; reads of cur done
    cur ^= 1;
  }
#undef STAGE

  // ---- epilogue: C/D layout col=lane&15, row=(lane>>4)*4+reg  [guide §3] ----
  const int cRow = (lane >> 4) * 4, cCol = lane & 15;
  int tj[4], ti[4][4];
#pragma unroll
  for (int n = 0; n < 4; ++n) tj[n] = tg[rowB0 + wc * 64 + n * 16 + cCol];
#pragma unroll
  for (int m = 0; m < 4; ++m)
#pragma unroll
    for (int r = 0; r < 4; ++r) ti[m][r] = tg[rowA0 + wr * 64 + m * 16 + cRow + r];

  float pc = 0.f, ps = 0.f, ns = 0.f;
#pragma unroll
  for (int m = 0; m < 4; ++m)
#pragma unroll
    for (int n = 0; n < 4; ++n)
#pragma unroll
      for (int r = 0; r < 4; ++r) {
        float s = acc[m][n][r];
        bool same = (ti[m][r] == tj[n]);
        if (same & (s < 0.9f)) { pc += 1.0f; ps += s; }
        if ((!same) & (s > 0.5f)) { ns += s; }
      }

#pragma unroll
  for (int off = 32; off > 0; off >>= 1) {
    pc += __shfl_down(pc, off);
    ps += __shfl_down(ps, off);
    ns += __shfl_down(ns, off);
  }
  __shared__ float red[3][4];
  if (lane == 0) { red[0][wv] = pc; red[1][wv] = ps; red[2][wv] = ns; }
  __syncthreads();
  if (tid == 0) {
    double w = (bi == bj) ? 1.0 : 2.0;  // off-diagonal tiles count twice
    double* slot = accd + (blockIdx.x & 31) * 3;  // 32 shadow slots: low contention
    atomicAdd(&slot[0], w * (double)(red[0][0] + red[0][1] + red[0][2] + red[0][3]));
    atomicAdd(&slot[1], w * (double)(red[1][0] + red[1][1] + red[1][2] + red[1][3]));
    atomicAdd(&slot[2], w * (double)(red[2][0] + red[2][1] + red[2][2] + red[2][3]));
  }
}

// ---------------- last-row stats in fp64 (sim<1.0 diagonal test) ----------------
__global__ void lastrow_kernel(const float* __restrict__ X, const int* __restrict__ tg,
                               double* __restrict__ accd) {
  int j = blockIdx.x * blockDim.x + threadIdx.x;
  const float4* xr = (const float4*)(X + (size_t)(N_ - 1) * D_);
  const float4* yj = (const float4*)(X + (size_t)j * D_);
  double s = 0.0;
#pragma unroll 4
  for (int k = 0; k < D_ / 4; ++k) {
    float4 a = xr[k], b = yj[k];
    s += (double)a.x * b.x + (double)a.y * b.y + (double)a.z * b.z + (double)a.w * b.w;
  }
  float sf = (float)s;
  bool same = (tg[j] == tg[N_ - 1]);
  float v[4] = {0.f, 0.f, 0.f, 0.f};
  if (same && sf < 1.0f) { v[0] = sf; v[1] = 1.f; }
  if (!same) { v[2] = sf; v[3] = 1.f; }
#pragma unroll
  for (int off = 32; off > 0; off >>= 1)
#pragma unroll
    for (int q = 0; q < 4; ++q) v[q] += __shfl_down(v[q], off);
  if ((threadIdx.x & 63) == 0)
#pragma unroll
    for (int q = 0; q < 4; ++q) atomicAdd(&accd[96 + q], (double)v[q]);
}

// ---------------- finalize ----------------
__global__ void finalize_kernel(const double* __restrict__ accd, float* __restrict__ out) {
  double pc = 0.0, ps = 0.0, ns = 0.0;
  for (int i = 0; i < 32; ++i) {
    pc += accd[i * 3 + 0];
    ps += accd[i * 3 + 1];
    ns += accd[i * 3 + 2];
  }
  double loss = (pc - ps + ns) / (double)N_;
  out[0] = (float)loss;
  out[1] = 0.0f;
  out[2] = (float)(accd[96] / fmax(accd[97], 1.0));
  out[3] = (float)(accd[98] / fmax(accd[99], 1.0));
}

extern "C" void kernel_launch(void* const* d_in, const int* in_sizes, int n_in,
                              void* d_out, int out_size, void* d_ws, size_t ws_size,
                              hipStream_t stream) {
  const float* X = (const float*)d_in[0];
  const int* tg = (const int*)d_in[1];
  float* out = (float*)d_out;
  double* accd = (double*)d_ws;
  __hip_bfloat16* Xb = (__hip_bfloat16*)((char*)d_ws + 1024);

  hipMemsetAsync(d_ws, 0, 1024, stream);  // zero all accumulator slots

  int n4 = N_ * D_ / 4;
  cvt_kernel<<<(n4 + 255) / 256, 256, 0, stream>>>((const float4*)X, (ushort4*)Xb, n4);

  simloss_kernel<<<NT, 256, 0, stream>>>(Xb, tg, accd);

  lastrow_kernel<<<N_ / 256, 256, 0, stream>>>(X, tg, accd);
  finalize_kernel<<<1, 1, 0, stream>>>(accd, out);
}

// Round 3
// 49.764 us; speedup vs baseline: 2.4545x; 1.4797x over previous
//
#include <hip/hip_runtime.h>
#include <hip/hip_bf16.h>

#define N_ 8192
#define D_ 256
#define BM 128
#define BK 32
#define NB (N_ / BM)            // 64
#define NT (NB * (NB + 1) / 2)  // 2080 triangular tiles
#define KSTEPS (D_ / BK)        // 8

typedef __bf16 bf16x8 __attribute__((ext_vector_type(8)));
typedef float f32x4 __attribute__((ext_vector_type(4)));

// ---------------- fp32 -> bf16 convert (+ zero the accumulators) ----------------
__global__ void cvt_kernel(const float4* __restrict__ in, ushort4* __restrict__ out, int n4,
                           double* __restrict__ accd) {
  int i = blockIdx.x * blockDim.x + threadIdx.x;
  if (blockIdx.x == 0 && threadIdx.x < 128) accd[threadIdx.x] = 0.0;  // 1 KB of slots
  if (i >= n4) return;
  float4 v = in[i];
  union { __hip_bfloat16 h[4]; ushort4 u; } t;
  t.h[0] = __float2bfloat16(v.x);
  t.h[1] = __float2bfloat16(v.y);
  t.h[2] = __float2bfloat16(v.z);
  t.h[3] = __float2bfloat16(v.w);
  out[i] = t.u;
}

// ws accumulator layout (doubles):
//  [32][3] slots {pos_cnt, pos_sim_sum, neg_sim_sum}   (0..95)
//  [96..99] lastrow {lp_sum, lp_cnt, ln_sum, ln_cnt}
__global__ __launch_bounds__(256, 4) void simloss_kernel(
    const __hip_bfloat16* __restrict__ Xb, const int* __restrict__ tg,
    double* __restrict__ accd) {
  __shared__ __align__(16) char lds[32768];  // A: buf*8192, B: 16384+buf*8192

  // ---- triangular tile decode (float sqrt + fixups) ----
  const int t = blockIdx.x;
  int bi = (int)(((2.0f * NB + 1.0f) -
                  sqrtf((2.0f * NB + 1.0f) * (2.0f * NB + 1.0f) - 8.0f * (float)t)) * 0.5f);
  if (bi < 0) bi = 0;
  if (bi > NB - 1) bi = NB - 1;
  while (((bi + 1) * NB - ((bi + 1) * bi) / 2) <= t) ++bi;
  while ((bi * NB - (bi * (bi - 1)) / 2) > t) --bi;
  const int bj = bi + (t - (bi * NB - (bi * (bi - 1)) / 2));

  const int tid = threadIdx.x;
  const int lane = tid & 63, wv = tid >> 6;
  const int wr = wv >> 1, wc = wv & 1;  // wave -> 64x64 sub-tile
  const int rowA0 = bi * BM, rowB0 = bj * BM;

  // ---- staging constants: chunk c -> row=c>>2, slot=c&3, srcslot = slot^((row>>1)&3)
  const int c0 = (wv * 2 + 0) * 64 + lane;
  const int c1 = (wv * 2 + 1) * 64 + lane;
  const int r0 = c0 >> 2, s0 = (c0 & 3) ^ ((r0 >> 1) & 3);
  const int r1 = c1 >> 2, s1 = (c1 & 3) ^ ((r1 >> 1) & 3);
  const __hip_bfloat16* gA0 = Xb + (size_t)(rowA0 + r0) * D_ + s0 * 8;
  const __hip_bfloat16* gA1 = Xb + (size_t)(rowA0 + r1) * D_ + s1 * 8;
  const __hip_bfloat16* gB0 = Xb + (size_t)(rowB0 + r0) * D_ + s0 * 8;
  const __hip_bfloat16* gB1 = Xb + (size_t)(rowB0 + r1) * D_ + s1 * 8;
  char* lA0 = lds + c0 * 16;
  char* lA1 = lds + c1 * 16;
  char* lB0 = lds + 16384 + c0 * 16;
  char* lB1 = lds + 16384 + c1 * 16;

#define GLDS(g, l) \
  __builtin_amdgcn_global_load_lds((const __attribute__((address_space(1))) void*)(g), \
                                   (__attribute__((address_space(3))) void*)(l), 16, 0, 0)
#define STAGE(buf, kt)                       \
  do {                                       \
    GLDS(gA0 + (kt) * BK, lA0 + (buf) * 8192); \
    GLDS(gA1 + (kt) * BK, lA1 + (buf) * 8192); \
    GLDS(gB0 + (kt) * BK, lB0 + (buf) * 8192); \
    GLDS(gB1 + (kt) * BK, lB1 + (buf) * 8192); \
  } while (0)

  // ---- fragment-read constants (swizzled: read slot = sl ^ ((fr>>1)&3)) ----
  const int fr = lane & 15, sl = lane >> 4;
  const int rswz = sl ^ ((fr >> 1) & 3);
  const int aoff = (wr * 64 + fr) * 64 + rswz * 16;  // bytes within A buffer
  const int boff = (wc * 64 + fr) * 64 + rswz * 16;  // bytes within B buffer

  f32x4 acc[4][4] = {};

  STAGE(0, 0);
  __syncthreads();
#pragma unroll
  for (int kt = 0; kt < KSTEPS; ++kt) {
    const int cur = kt & 1;
    if (kt < KSTEPS - 1) STAGE(cur ^ 1, kt + 1);  // prefetch next K-chunk
    const char* Ab = lds + cur * 8192;
    const char* Bb = lds + 16384 + cur * 8192;
    bf16x8 af[4], bfr[4];
#pragma unroll
    for (int m = 0; m < 4; ++m) af[m] = *(const bf16x8*)(Ab + aoff + m * 1024);
#pragma unroll
    for (int n = 0; n < 4; ++n) bfr[n] = *(const bf16x8*)(Bb + boff + n * 1024);
#pragma unroll
    for (int m = 0; m < 4; ++m)
#pragma unroll
      for (int n = 0; n < 4; ++n)
        acc[m][n] = __builtin_amdgcn_mfma_f32_16x16x32_bf16(af[m], bfr[n], acc[m][n], 0, 0, 0);
    __syncthreads();
  }
#undef STAGE
#undef GLDS

  // ---- epilogue: C/D layout col=lane&15, row=(lane>>4)*4+reg  [guide §3] ----
  const int cRow = (lane >> 4) * 4, cCol = lane & 15;
  int tj[4], ti[4][4];
#pragma unroll
  for (int n = 0; n < 4; ++n) tj[n] = tg[rowB0 + wc * 64 + n * 16 + cCol];
#pragma unroll
  for (int m = 0; m < 4; ++m)
#pragma unroll
    for (int r = 0; r < 4; ++r) ti[m][r] = tg[rowA0 + wr * 64 + m * 16 + cRow + r];

  float pc = 0.f, ps = 0.f, ns = 0.f;
#pragma unroll
  for (int m = 0; m < 4; ++m)
#pragma unroll
    for (int n = 0; n < 4; ++n)
#pragma unroll
      for (int r = 0; r < 4; ++r) {
        float s = acc[m][n][r];
        bool same = (ti[m][r] == tj[n]);
        if (same & (s < 0.9f)) { pc += 1.0f; ps += s; }
        if ((!same) & (s > 0.5f)) { ns += s; }
      }

  // ---- last-row (row 8191) stats: column 8191 lives at bj=63, wc=1, n=3, cCol=15 ----
  if (bj == NB - 1 && wc == 1 && cCol == 15) {
    const int tlast = tj[3];  // tg[8191]
    float lps = 0.f, lns = 0.f, lpc = 0.f, lnc = 0.f;
#pragma unroll
    for (int m = 0; m < 4; ++m)
#pragma unroll
      for (int r = 0; r < 4; ++r) {
        float s = acc[m][3][r];
        bool same = (ti[m][r] == tlast);
        if (same && s < 1.0f) { lps += s; lpc += 1.f; }
        if (!same) { lns += s; lnc += 1.f; }
      }
    atomicAdd(&accd[96], (double)lps);
    atomicAdd(&accd[97], (double)lpc);
    atomicAdd(&accd[98], (double)lns);
    atomicAdd(&accd[99], (double)lnc);
  }

  // ---- block reduction (reuse LDS) + per-slot atomics ----
#pragma unroll
  for (int off = 32; off > 0; off >>= 1) {
    pc += __shfl_down(pc, off);
    ps += __shfl_down(ps, off);
    ns += __shfl_down(ns, off);
  }
  float* red = (float*)lds;  // safe: all LDS traffic drained by final barrier
  if (lane == 0) { red[0 * 4 + wv] = pc; red[1 * 4 + wv] = ps; red[2 * 4 + wv] = ns; }
  __syncthreads();
  if (tid == 0) {
    double w = (bi == bj) ? 1.0 : 2.0;  // off-diagonal tiles count twice
    double* slot = accd + (blockIdx.x & 31) * 3;
    atomicAdd(&slot[0], w * (double)(red[0] + red[1] + red[2] + red[3]));
    atomicAdd(&slot[1], w * (double)(red[4] + red[5] + red[6] + red[7]));
    atomicAdd(&slot[2], w * (double)(red[8] + red[9] + red[10] + red[11]));
  }
}

// ---------------- finalize ----------------
__global__ void finalize_kernel(const double* __restrict__ accd, float* __restrict__ out) {
  double pc = 0.0, ps = 0.0, ns = 0.0;
#pragma unroll
  for (int i = 0; i < 32; ++i) {
    pc += accd[i * 3 + 0];
    ps += accd[i * 3 + 1];
    ns += accd[i * 3 + 2];
  }
  double loss = (pc - ps + ns) / (double)N_;
  out[0] = (float)loss;
  out[1] = 0.0f;  // prec: reference never increments c
  out[2] = (float)(accd[96] / fmax(accd[97], 1.0));
  out[3] = (float)(accd[98] / fmax(accd[99], 1.0));
}

extern "C" void kernel_launch(void* const* d_in, const int* in_sizes, int n_in,
                              void* d_out, int out_size, void* d_ws, size_t ws_size,
                              hipStream_t stream) {
  const float* X = (const float*)d_in[0];
  const int* tg = (const int*)d_in[1];
  float* out = (float*)d_out;
  double* accd = (double*)d_ws;
  __hip_bfloat16* Xb = (__hip_bfloat16*)((char*)d_ws + 1024);

  int n4 = N_ * D_ / 4;
  cvt_kernel<<<(n4 + 255) / 256, 256, 0, stream>>>((const float4*)X, (ushort4*)Xb, n4, accd);

  simloss_kernel<<<NT, 256, 0, stream>>>(Xb, tg, accd);

  finalize_kernel<<<1, 1, 0, stream>>>(accd, out);
}